// Round 10
// baseline (178.777 us; speedup 1.0000x reference)
//
#include <hip/hip_runtime.h>
#include <hip/hip_bf16.h>
#include <cstdint>

// Problem constants (reference: BATCH=4096, N_VIEWS=2, T=0.07, D=128 -> N=8192)
#define NROWS 8192
#define FDIM  128
#define HALF_N 4096

typedef float f32x4 __attribute__((ext_vector_type(4)));

// k1 = log2(e)/T so exp((s-1)/T) = exp2(k1*s - k1)
#define K1 (1.4426950408889634f / 0.07f)

#if __has_builtin(__builtin_amdgcn_exp2f)
#define EXP2(x) __builtin_amdgcn_exp2f(x)       // raw v_exp_f32
#else
#define EXP2(x) exp2f(x)
#endif

// Fragment-packed fp8(e4m3) layout, unit-identical to the verified bf16 one
// (bytes instead of shorts): frag (rb, ks) is 512 B at flat i64 index
// (rb*4+ks)*64 + lane; lane = quad*16 + (r&15) holds row r = rb*16+(lane&15),
// k = ks*32 + quad*8 .. +8 (one byte each). A wave loads one A/B fragment of
// mfma_f32_16x16x32_fp8_fp8 (2 VGPRs) with ONE coalesced global_load_dwordx2.
// Total packed size: 1 MB.

// ---------------------------------------------------------------------------
// Kernel 1: L2-normalize rows (fp32, matching ref), quantize to fp8-e4m3,
// write fragment-packed. Also zero-inits esum_g.
// ---------------------------------------------------------------------------
__global__ void __launch_bounds__(256) normalize_kernel(const float* __restrict__ f,
                                                        unsigned char* __restrict__ packed,
                                                        float* __restrict__ esum_g) {
    const int row  = blockIdx.x * 4 + (threadIdx.x >> 6);
    const int lane = threadIdx.x & 63;           // elements k = 2*lane, 2*lane+1
    const float2 v = ((const float2*)(f + (size_t)row * FDIM))[lane];
    float ss = v.x * v.x + v.y * v.y;
    #pragma unroll
    for (int m = 1; m < 64; m <<= 1) ss += __shfl_xor(ss, m);
    const float scale = 1.0f / fmaxf(sqrtf(ss), 1e-12f);

    // byte offset of (row, k=2*lane): ks = lane>>4, quad = (lane>>2)&3
    const int off = ((((row >> 4) * 4 + (lane >> 4)) * 64)
                     + ((lane >> 2) & 3) * 16 + (row & 15)) * 8 + 2 * (lane & 3);
    const int pk2 = __builtin_amdgcn_cvt_pk_fp8_f32(v.x * scale, v.y * scale,
                                                    0, false);   // byte0=x, byte1=y
    *(unsigned short*)(packed + off) = (unsigned short)(pk2 & 0xffff);

    if (threadIdx.x < 4) esum_g[blockIdx.x * 4 + threadIdx.x] = 0.0f;
}

// e4m3fn (OCP) byte -> float, |v| <= 1 in our data (no NaN path needed)
__device__ __forceinline__ float fp8_to_f32(unsigned b) {
    const unsigned e = (b >> 3) & 15, m = b & 7;
    float v = e ? __uint_as_float(((e + 120u) << 23) | (m << 20))
                : (float)m * 0.001953125f;       // subnormal: m * 2^-9
    return (b & 0x80) ? -v : v;
}

// ---------------------------------------------------------------------------
// Kernel 2: full-matrix fused sim+exp+rowsum, fp8 operands, park=64.
// 4096 compute waves: wave = (strip of 64 rows, jg of 256 cols, 16 cbs).
// Block = 4 waves, same jg (B-streams alias in CU L1), strips sg*4..+3.
// Grid 1024 = 4 blocks/CU, __launch_bounds__(256,4); VGPR ~90 (a_reg only
// 32 regs at fp8 — round-9's spill is structurally impossible here).
// Aggregate per-CU budgets: matrix 8.3us + VALU ~6us + L1 134MB=3.4us.
// esum includes the diagonal term (subtracted in final via diag_g; exact
// cancellation — MFMA sim_ii and scalar diag consume identical fp8 bytes).
// Blocks 1024..1055: pos_i = <f_i, f_(i^4096)>, diag_i = exp((<f_i,f_i>-1)/T),
// both from the fp8 packed data.
// ---------------------------------------------------------------------------
__global__ void __launch_bounds__(256, 4) sim_kernel(const unsigned char* __restrict__ pk,
                                                     float* __restrict__ esum_g,
                                                     float* __restrict__ pos_g,
                                                     float* __restrict__ diag_g) {
    const long* P = (const long*)pk;             // 8-byte fragment units

    if (blockIdx.x >= 1024) {
        // ---- pos/diag path: one thread per row ----
        const int i  = (blockIdx.x - 1024) * 256 + threadIdx.x;
        const int ip = i ^ HALF_N;
        float dot = 0.f, self = 0.f;
        #pragma unroll
        for (int cc = 0; cc < 16; cc++) {        // cc = ks*4 + quad
            const unsigned long a =
                (unsigned long)P[((i  >> 4) * 4 + (cc >> 2)) * 64 + (cc & 3) * 16 + (i  & 15)];
            const unsigned long b =
                (unsigned long)P[((ip >> 4) * 4 + (cc >> 2)) * 64 + (cc & 3) * 16 + (ip & 15)];
            #pragma unroll
            for (int q = 0; q < 8; q++) {
                const float av = fp8_to_f32((unsigned)(a >> (8 * q)) & 0xff);
                const float bv = fp8_to_f32((unsigned)(b >> (8 * q)) & 0xff);
                dot  = __builtin_fmaf(av, bv, dot);
                self = __builtin_fmaf(av, av, self);
            }
        }
        pos_g[i]  = dot;
        diag_g[i] = EXP2(__builtin_fmaf(self, K1, -K1));
        return;
    }

    const int tid   = threadIdx.x;
    const int w     = tid >> 6;
    const int lane  = tid & 63;
    const int quad  = lane >> 4;
    const int l16   = lane & 15;
    const int jg    = blockIdx.x & 31;           // col group (256 cols), SHARED
    const int strip = (blockIdx.x >> 5) * 4 + w; // 0..127: rows strip*64..+64

    // A fragments for this wave's 64 rows, parked: a_reg[ks][fr] (32 VGPR)
    long a_reg[4][4];
    #pragma unroll
    for (int fr = 0; fr < 4; fr++)
        #pragma unroll
        for (int ks = 0; ks < 4; ks++)
            a_reg[ks][fr] = P[((strip * 4 + fr) * 4 + ks) * 64 + lane];

    float ep[4][4];                              // [fr][r] row partials
    #pragma unroll
    for (int a = 0; a < 4; a++)
        #pragma unroll
        for (int b = 0; b < 4; b++) ep[a][b] = 0.0f;

    const int cb0 = jg * 16;                     // 16 col-blocks of 16 cols
    long bb[2][4];
    #pragma unroll
    for (int ks = 0; ks < 4; ks++)
        bb[0][ks] = P[(cb0 * 4 + ks) * 64 + lane];

    #pragma unroll 4
    for (int t = 0; t < 16; t++) {
        if (t < 15) {                            // prefetch next cb (ping-pong)
            #pragma unroll
            for (int ks = 0; ks < 4; ks++)
                bb[(t + 1) & 1][ks] = P[((cb0 + t + 1) * 4 + ks) * 64 + lane];
        }

        f32x4 acc[4];
        #pragma unroll
        for (int fr = 0; fr < 4; fr++) acc[fr] = (f32x4){0.f, 0.f, 0.f, 0.f};
        #pragma unroll
        for (int ks = 0; ks < 4; ks++)
            #pragma unroll
            for (int fr = 0; fr < 4; fr++)
                acc[fr] = __builtin_amdgcn_mfma_f32_16x16x32_fp8_fp8(
                              a_reg[ks][fr], bb[t & 1][ks], acc[fr], 0, 0, 0);

        #pragma unroll
        for (int fr = 0; fr < 4; fr++)
            #pragma unroll
            for (int r = 0; r < 4; r++)
                ep[fr][r] += EXP2(__builtin_fmaf(acc[fr][r], K1, -K1));
    }

    // reduce row partials across the 16 column-lanes, commit once per wave
    #pragma unroll
    for (int fr = 0; fr < 4; fr++)
        #pragma unroll
        for (int r = 0; r < 4; r++) {
            float v = ep[fr][r];
            #pragma unroll
            for (int m = 1; m < 16; m <<= 1) v += __shfl_xor(v, m);
            if (l16 == 0)
                atomicAdd(&esum_g[strip * 64 + fr * 16 + quad * 4 + r], v);
        }
}

// ---------------------------------------------------------------------------
// Kernel 3: loss_i = ln(esum_i - diag_i) + 1/T - pos_i/T ; out = mean(loss).
// ---------------------------------------------------------------------------
__global__ void __launch_bounds__(256) final_kernel(const float* __restrict__ esum_g,
                                                    const float* __restrict__ pos_g,
                                                    const float* __restrict__ diag_g,
                                                    float* __restrict__ out) {
    const int tid = threadIdx.x;
    const float invT = 1.0f / 0.07f;
    float acc = 0.0f;
    for (int i = tid; i < NROWS; i += 256)
        acc += logf(esum_g[i] - diag_g[i]) + invT - pos_g[i] * invT;
    #pragma unroll
    for (int m = 1; m < 64; m <<= 1) acc += __shfl_xor(acc, m);
    __shared__ float ws[4];
    if ((tid & 63) == 0) ws[tid >> 6] = acc;
    __syncthreads();
    if (tid == 0) out[0] = (ws[0] + ws[1] + ws[2] + ws[3]) * (1.0f / (float)NROWS);
}

// ---------------------------------------------------------------------------
extern "C" void kernel_launch(void* const* d_in, const int* in_sizes, int n_in,
                              void* d_out, int out_size, void* d_ws, size_t ws_size,
                              hipStream_t stream) {
    const float* features = (const float*)d_in[0];
    float* out = (float*)d_out;

    char* ws = (char*)d_ws;
    unsigned char* packed = (unsigned char*)ws;                          // 1 MB
    float* esum_g = (float*)(ws + 2097152);                              // 32 KB
    float* pos_g  = (float*)(ws + 2097152 + 32768);                      // 32 KB
    float* diag_g = (float*)(ws + 2097152 + 65536);                      // 32 KB

    normalize_kernel<<<NROWS / 4, 256, 0, stream>>>(features, packed, esum_g);

    sim_kernel<<<1024 + NROWS / 256, 256, 0, stream>>>(packed, esum_g, pos_g, diag_g);

    final_kernel<<<1, 256, 0, stream>>>(esum_g, pos_g, diag_g, out);
}

// Round 11
// 93.268 us; speedup vs baseline: 1.9168x; 1.9168x over previous
//
#include <hip/hip_runtime.h>
#include <hip/hip_bf16.h>
#include <cstdint>

// Problem constants (reference: BATCH=4096, N_VIEWS=2, T=0.07, D=128 -> N=8192)
#define NROWS 8192
#define FDIM  128
#define HALF_N 4096

typedef short bf16x8 __attribute__((ext_vector_type(8)));   // 8 bf16 = 4 VGPRs
typedef float f32x16 __attribute__((ext_vector_type(16)));  // 32x32 accumulator

// k1 = log2(e)/T so exp((s-1)/T) = exp2(k1*s - k1)
#define K1 (1.4426950408889634f / 0.07f)

#if __has_builtin(__builtin_amdgcn_exp2f)
#define EXP2(x) __builtin_amdgcn_exp2f(x)       // raw v_exp_f32
#else
#define EXP2(x) exp2f(x)
#endif

// Fragment-packed bf16 layout for mfma_f32_32x32x16_bf16:
//   frag (rb32, ks), rb32 = 32-row block, ks = 0..7 (16 k each), at flat
//   bf16x8 index (rb32*8 + ks)*64 + lane; lane = half*32 + (row&31),
//   half = lane>>5, holding row = rb32*32 + (lane&31),
//   k = ks*16 + half*8 + j (j = 0..7).   [A/B-operand register image]
// One coalesced global_load_dwordx4 per fragment. 2 MB total.

// ---------------------------------------------------------------------------
// Kernel 1: L2-normalize rows (fp32, matching ref), write fragment-packed
// bf16 (32-row-block layout). Also zero-inits esum_g.
// ---------------------------------------------------------------------------
__global__ void __launch_bounds__(256) normalize_kernel(const float* __restrict__ f,
                                                        short* __restrict__ packed,
                                                        float* __restrict__ esum_g) {
    const int row  = blockIdx.x * 4 + (threadIdx.x >> 6);
    const int lane = threadIdx.x & 63;           // elements k = 2*lane, 2*lane+1
    const float2 v = ((const float2*)(f + (size_t)row * FDIM))[lane];
    float ss = v.x * v.x + v.y * v.y;
    #pragma unroll
    for (int m = 1; m < 64; m <<= 1) ss += __shfl_xor(ss, m);
    const float scale = 1.0f / fmaxf(sqrtf(ss), 1e-12f);

    // (row, k=2*lane): ks = lane>>3, half = (lane>>2)&1, j = 2*(lane&3)
    const int off = ((((row >> 5) * 8 + (lane >> 3)) * 64)
                     + ((lane >> 2) & 1) * 32 + (row & 31)) * 8 + 2 * (lane & 3);
    __hip_bfloat16 b0 = __float2bfloat16(v.x * scale);
    __hip_bfloat16 b1 = __float2bfloat16(v.y * scale);
    unsigned u = (unsigned)*(unsigned short*)&b0
               | ((unsigned)*(unsigned short*)&b1 << 16);
    *(unsigned*)(packed + off) = u;              // 4B-aligned (off is even)

    if (threadIdx.x < 4) esum_g[blockIdx.x * 4 + threadIdx.x] = 0.0f;
}

__device__ __forceinline__ float2 bf2_to_f2(unsigned u) {
    return make_float2(__uint_as_float(u << 16),
                       __uint_as_float(u & 0xffff0000u));
}

// ---------------------------------------------------------------------------
// Kernel 2: full-matrix fused sim+exp+rowsum — round-8 skeleton, 32x32x16.
// 4096 compute waves: wave = (strip of 32 rows, j of 512 cols, 16 cbs of
// 32 cols). Block = 4 waves sharing j (B-streams alias in CU L1), strips
// sg*4..+3. Grid 1024 = 4 blocks/CU. Per cb: 8 B-frag loads + 8 MFMA
// (32x32x16 — HALF the issue slots of round 8's 16x16x32, same FLOP and
// same bytes) + 16 exp. a_reg 32 VGPR; acc 16 (AGPR); ep 16.
// esum includes the diagonal (subtracted exactly in final via diag_g).
// Blocks 1024..1055: pos_i = <f_i, f_(i^4096)>, diag_i = exp((<f_i,f_i>-1)/T).
// ---------------------------------------------------------------------------
__global__ void __launch_bounds__(256, 4) sim_kernel(const short* __restrict__ pk,
                                                     float* __restrict__ esum_g,
                                                     float* __restrict__ pos_g,
                                                     float* __restrict__ diag_g) {
    if (blockIdx.x >= 1024) {
        // ---- pos/diag path: one thread per row ----
        const int i  = (blockIdx.x - 1024) * 256 + threadIdx.x;
        const int ip = i ^ HALF_N;
        const uint4* P = (const uint4*)pk;
        float dot = 0.f, self = 0.f;
        #pragma unroll
        for (int cc = 0; cc < 16; cc++) {        // cc = ks*2 + half
            const uint4 a = P[((i  >> 5) * 8 + (cc >> 1)) * 64 + (cc & 1) * 32 + (i  & 31)];
            const uint4 b = P[((ip >> 5) * 8 + (cc >> 1)) * 64 + (cc & 1) * 32 + (ip & 31)];
            const unsigned au[4] = {a.x, a.y, a.z, a.w};
            const unsigned bu[4] = {b.x, b.y, b.z, b.w};
            #pragma unroll
            for (int q = 0; q < 4; q++) {
                const float2 av = bf2_to_f2(au[q]);
                const float2 bv = bf2_to_f2(bu[q]);
                dot  = __builtin_fmaf(av.x, bv.x, __builtin_fmaf(av.y, bv.y, dot));
                self = __builtin_fmaf(av.x, av.x, __builtin_fmaf(av.y, av.y, self));
            }
        }
        pos_g[i]  = dot;
        diag_g[i] = EXP2(__builtin_fmaf(self, K1, -K1));
        return;
    }

    const int tid   = threadIdx.x;
    const int w     = tid >> 6;
    const int lane  = tid & 63;
    const int half  = lane >> 5;
    const int l32   = lane & 31;
    const int j     = blockIdx.x & 15;           // col group (512 cols), SHARED
    const int strip = (blockIdx.x >> 4) * 4 + w; // 0..255: rows strip*32..+32
    const bf16x8* P = (const bf16x8*)pk;

    // A fragments for this wave's 32 rows, parked: a_reg[ks] (32 VGPR)
    bf16x8 a_reg[8];
    #pragma unroll
    for (int ks = 0; ks < 8; ks++)
        a_reg[ks] = P[(strip * 8 + ks) * 64 + lane];

    float ep[16];                                // per-lane row partials
    #pragma unroll
    for (int r = 0; r < 16; r++) ep[r] = 0.0f;

    const int cb0 = j * 16;                      // 16 col-blocks of 32 cols

    #pragma unroll 4
    for (int cb = 0; cb < 16; cb++) {
        bf16x8 b[8];
        #pragma unroll
        for (int ks = 0; ks < 8; ks++)
            b[ks] = P[((cb0 + cb) * 8 + ks) * 64 + lane];

        f32x16 acc = {0.f, 0.f, 0.f, 0.f, 0.f, 0.f, 0.f, 0.f,
                      0.f, 0.f, 0.f, 0.f, 0.f, 0.f, 0.f, 0.f};
        #pragma unroll
        for (int ks = 0; ks < 8; ks++)
            acc = __builtin_amdgcn_mfma_f32_32x32x16_bf16(a_reg[ks], b[ks],
                                                          acc, 0, 0, 0);

        #pragma unroll
        for (int r = 0; r < 16; r++)
            ep[r] += EXP2(__builtin_fmaf(acc[r], K1, -K1));
    }

    // reduce row partials across the 32 column-lanes, commit once per wave.
    // C/D layout (m74/m101): col = lane&31, row = (reg&3)+8*(reg>>2)+4*half.
    #pragma unroll
    for (int r = 0; r < 16; r++) {
        float v = ep[r];
        #pragma unroll
        for (int m = 1; m < 32; m <<= 1) v += __shfl_xor(v, m);
        if (l32 == 0)
            atomicAdd(&esum_g[strip * 32 + (r & 3) + 8 * (r >> 2) + 4 * half], v);
    }
}

// ---------------------------------------------------------------------------
// Kernel 3: loss_i = ln(esum_i - diag_i) + 1/T - pos_i/T ; out = mean(loss).
// ---------------------------------------------------------------------------
__global__ void __launch_bounds__(256) final_kernel(const float* __restrict__ esum_g,
                                                    const float* __restrict__ pos_g,
                                                    const float* __restrict__ diag_g,
                                                    float* __restrict__ out) {
    const int tid = threadIdx.x;
    const float invT = 1.0f / 0.07f;
    float acc = 0.0f;
    for (int i = tid; i < NROWS; i += 256)
        acc += logf(esum_g[i] - diag_g[i]) + invT - pos_g[i] * invT;
    #pragma unroll
    for (int m = 1; m < 64; m <<= 1) acc += __shfl_xor(acc, m);
    __shared__ float ws[4];
    if ((tid & 63) == 0) ws[tid >> 6] = acc;
    __syncthreads();
    if (tid == 0) out[0] = (ws[0] + ws[1] + ws[2] + ws[3]) * (1.0f / (float)NROWS);
}

// ---------------------------------------------------------------------------
extern "C" void kernel_launch(void* const* d_in, const int* in_sizes, int n_in,
                              void* d_out, int out_size, void* d_ws, size_t ws_size,
                              hipStream_t stream) {
    const float* features = (const float*)d_in[0];
    float* out = (float*)d_out;

    char* ws = (char*)d_ws;
    short* packed = (short*)ws;                                          // 2 MB
    float* esum_g = (float*)(ws + 2097152);                              // 32 KB
    float* pos_g  = (float*)(ws + 2097152 + 32768);                      // 32 KB
    float* diag_g = (float*)(ws + 2097152 + 65536);                      // 32 KB

    normalize_kernel<<<NROWS / 4, 256, 0, stream>>>(features, packed, esum_g);

    sim_kernel<<<1024 + NROWS / 256, 256, 0, stream>>>(packed, esum_g, pos_g, diag_g);

    final_kernel<<<1, 256, 0, stream>>>(esum_g, pos_g, diag_g, out);
}

// Round 12
// 89.816 us; speedup vs baseline: 1.9905x; 1.0384x over previous
//
#include <hip/hip_runtime.h>
#include <hip/hip_bf16.h>
#include <cstdint>

// Problem constants (reference: BATCH=4096, N_VIEWS=2, T=0.07, D=128 -> N=8192)
#define NROWS 8192
#define FDIM  128
#define HALF_N 4096

typedef short bf16x8 __attribute__((ext_vector_type(8)));   // 8 bf16 = 4 VGPRs
typedef float f32x4  __attribute__((ext_vector_type(4)));

// k1 = log2(e)/T so exp((s-1)/T) = exp2(k1*s - k1)
#define K1 (1.4426950408889634f / 0.07f)

#if __has_builtin(__builtin_amdgcn_exp2f)
#define EXP2(x) __builtin_amdgcn_exp2f(x)       // raw v_exp_f32
#else
#define EXP2(x) exp2f(x)
#endif

// Fragment-packed layout of the normalized bf16 matrix:
//   frag (rb, ks) at flat bf16x8 index (rb*4+ks)*64 + lane,
//   lane = quad*16 + (r&15) holds row r = rb*16+(lane&15), k = ks*32+quad*8..+8.
// One coalesced global_load_dwordx4 per fragment. 2 MB total.
//
// SESSION VERDICT (rounds 0-11): this round-8 structure is the best found
// (total 88.9 us). sim ~30 us is the serialized sum of matrix (8.3) +
// exp VALU (~6) + B-fragment L1 delivery (~14) and is invariant to
// occupancy (2 vs 4 waves/SIMD), prefetch depth, A-park size (32/64/128 —
// larger parks spill), dtype (fp8 spills), and MFMA shape (16x16 vs 32x32).
// Symmetry halving is memory-system-poisoned (cross-XCD atomics: round 6;
// partial-line scatter stores: round 7). Fill/restore poison ≈ 52 us floor.

// ---------------------------------------------------------------------------
// Kernel 1: L2-normalize rows (fp32, matching ref), write fragment-packed
// bf16. Also zero-inits esum_g.
// ---------------------------------------------------------------------------
__global__ void __launch_bounds__(256) normalize_kernel(const float* __restrict__ f,
                                                        short* __restrict__ packed,
                                                        float* __restrict__ esum_g) {
    const int row  = blockIdx.x * 4 + (threadIdx.x >> 6);
    const int lane = threadIdx.x & 63;           // element k = 2*lane, 2*lane+1
    const float2 v = ((const float2*)(f + (size_t)row * FDIM))[lane];
    float ss = v.x * v.x + v.y * v.y;
    #pragma unroll
    for (int m = 1; m < 64; m <<= 1) ss += __shfl_xor(ss, m);
    const float scale = 1.0f / fmaxf(sqrtf(ss), 1e-12f);

    const int off = ((((row >> 4) * 4 + (lane >> 4)) * 64)
                     + ((lane >> 2) & 3) * 16 + (row & 15)) * 8 + 2 * (lane & 3);
    __hip_bfloat16 b0 = __float2bfloat16(v.x * scale);
    __hip_bfloat16 b1 = __float2bfloat16(v.y * scale);
    unsigned u = (unsigned)*(unsigned short*)&b0
               | ((unsigned)*(unsigned short*)&b1 << 16);
    *(unsigned*)(packed + off) = u;              // 4B-aligned (off is even)

    if (threadIdx.x < 4) esum_g[blockIdx.x * 4 + threadIdx.x] = 0.0f;
}

__device__ __forceinline__ float2 bf2_to_f2(unsigned u) {
    return make_float2(__uint_as_float(u << 16),
                       __uint_as_float(u & 0xffff0000u));
}

// ---------------------------------------------------------------------------
// Kernel 2: full-matrix fused sim+exp+rowsum (round-8 best configuration).
// 4096 compute waves: wave = (strip of 32 rows, j of 512 cols). Block = 4
// waves sharing j over strips sg*4..+3 (B-stream aliases in CU L1).
// Grid 1024 = 4 blocks/CU, __launch_bounds__(256,4). A parked in 32 VGPR;
// per cb (16 cols): 4 B-frag loads + 8 MFMA + 8 exp2 per lane; unroll-8.
// esum includes the diagonal term (subtracted in final via diag_g).
// Blocks 1024..1055: pos_i = <f_i, f_(i^4096)>, diag_i = exp((<f_i,f_i>-1)/T).
// ---------------------------------------------------------------------------
__global__ void __launch_bounds__(256, 4) sim_kernel(const short* __restrict__ pk,
                                                     float* __restrict__ esum_g,
                                                     float* __restrict__ pos_g,
                                                     float* __restrict__ diag_g) {
    if (blockIdx.x >= 1024) {
        // ---- pos/diag path: one thread per row ----
        const int i  = (blockIdx.x - 1024) * 256 + threadIdx.x;
        const int ip = i ^ HALF_N;
        const uint4* P = (const uint4*)pk;
        float dot = 0.f, self = 0.f;
        #pragma unroll
        for (int cc = 0; cc < 16; cc++) {        // cc = ks*4 + quad
            const uint4 a = P[((i  >> 4) * 4 + (cc >> 2)) * 64 + (cc & 3) * 16 + (i  & 15)];
            const uint4 b = P[((ip >> 4) * 4 + (cc >> 2)) * 64 + (cc & 3) * 16 + (ip & 15)];
            const unsigned au[4] = {a.x, a.y, a.z, a.w};
            const unsigned bu[4] = {b.x, b.y, b.z, b.w};
            #pragma unroll
            for (int q = 0; q < 4; q++) {
                const float2 av = bf2_to_f2(au[q]);
                const float2 bv = bf2_to_f2(bu[q]);
                dot  = __builtin_fmaf(av.x, bv.x, __builtin_fmaf(av.y, bv.y, dot));
                self = __builtin_fmaf(av.x, av.x, __builtin_fmaf(av.y, av.y, self));
            }
        }
        pos_g[i]  = dot;
        diag_g[i] = EXP2(__builtin_fmaf(self, K1, -K1));
        return;
    }

    const int tid   = threadIdx.x;
    const int w     = tid >> 6;
    const int lane  = tid & 63;
    const int quad  = lane >> 4;
    const int l16   = lane & 15;
    const int j     = blockIdx.x & 15;           // col group (512 cols), SHARED
    const int strip = (blockIdx.x >> 4) * 4 + w; // 0..255: rows strip*32..+32
    const bf16x8* P = (const bf16x8*)pk;

    // A fragments for this wave's 32 rows, parked: a_reg[ks][fr] (32 VGPR)
    bf16x8 a_reg[4][2];
    #pragma unroll
    for (int fr = 0; fr < 2; fr++)
        #pragma unroll
        for (int ks = 0; ks < 4; ks++)
            a_reg[ks][fr] = P[(((strip * 2 + fr) * 4) + ks) * 64 + lane];

    float ep[2][4];                              // [fr][r] row partials
    #pragma unroll
    for (int a = 0; a < 2; a++)
        #pragma unroll
        for (int b = 0; b < 4; b++) ep[a][b] = 0.0f;

    const int cb0 = j * 32;                      // 32 col-blocks of 16

    #pragma unroll 8
    for (int cb = 0; cb < 32; cb++) {
        bf16x8 b[4];
        #pragma unroll
        for (int ks = 0; ks < 4; ks++)
            b[ks] = P[((cb0 + cb) * 4 + ks) * 64 + lane];

        f32x4 acc[2];
        #pragma unroll
        for (int fr = 0; fr < 2; fr++) acc[fr] = (f32x4){0.f, 0.f, 0.f, 0.f};
        #pragma unroll
        for (int ks = 0; ks < 4; ks++)
            #pragma unroll
            for (int fr = 0; fr < 2; fr++)
                acc[fr] = __builtin_amdgcn_mfma_f32_16x16x32_bf16(
                              a_reg[ks][fr], b[ks], acc[fr], 0, 0, 0);

        #pragma unroll
        for (int fr = 0; fr < 2; fr++)
            #pragma unroll
            for (int r = 0; r < 4; r++)
                ep[fr][r] += EXP2(__builtin_fmaf(acc[fr][r], K1, -K1));
    }

    // reduce row partials across the 16 column-lanes, commit once per wave
    #pragma unroll
    for (int fr = 0; fr < 2; fr++)
        #pragma unroll
        for (int r = 0; r < 4; r++) {
            float v = ep[fr][r];
            #pragma unroll
            for (int m = 1; m < 16; m <<= 1) v += __shfl_xor(v, m);
            if (l16 == 0)
                atomicAdd(&esum_g[strip * 32 + fr * 16 + quad * 4 + r], v);
        }
}

// ---------------------------------------------------------------------------
// Kernel 3: loss_i = ln(esum_i - diag_i) + 1/T - pos_i/T ; out = mean(loss).
// ---------------------------------------------------------------------------
__global__ void __launch_bounds__(256) final_kernel(const float* __restrict__ esum_g,
                                                    const float* __restrict__ pos_g,
                                                    const float* __restrict__ diag_g,
                                                    float* __restrict__ out) {
    const int tid = threadIdx.x;
    const float invT = 1.0f / 0.07f;
    float acc = 0.0f;
    for (int i = tid; i < NROWS; i += 256)
        acc += logf(esum_g[i] - diag_g[i]) + invT - pos_g[i] * invT;
    #pragma unroll
    for (int m = 1; m < 64; m <<= 1) acc += __shfl_xor(acc, m);
    __shared__ float ws[4];
    if ((tid & 63) == 0) ws[tid >> 6] = acc;
    __syncthreads();
    if (tid == 0) out[0] = (ws[0] + ws[1] + ws[2] + ws[3]) * (1.0f / (float)NROWS);
}

// ---------------------------------------------------------------------------
extern "C" void kernel_launch(void* const* d_in, const int* in_sizes, int n_in,
                              void* d_out, int out_size, void* d_ws, size_t ws_size,
                              hipStream_t stream) {
    const float* features = (const float*)d_in[0];
    float* out = (float*)d_out;

    char* ws = (char*)d_ws;
    short* packed = (short*)ws;                                          // 2 MB
    float* esum_g = (float*)(ws + 2097152);                              // 32 KB
    float* pos_g  = (float*)(ws + 2097152 + 32768);                      // 32 KB
    float* diag_g = (float*)(ws + 2097152 + 65536);                      // 32 KB

    normalize_kernel<<<NROWS / 4, 256, 0, stream>>>(features, packed, esum_g);

    sim_kernel<<<1024 + NROWS / 256, 256, 0, stream>>>(packed, esum_g, pos_g, diag_g);

    final_kernel<<<1, 256, 0, stream>>>(esum_g, pos_g, diag_g, out);
}